// Round 10
// baseline (110.489 us; speedup 1.0000x reference)
//
#include <hip/hip_runtime.h>
#include <hip/hip_bf16.h>

#define N_NODES 100000
#define N_EDGES 1600000
#define IN_F 256
#define OUT_F 128

typedef __attribute__((ext_vector_type(8))) __bf16 bf16x8;
typedef __attribute__((ext_vector_type(4))) float f32x4;

__device__ __forceinline__ unsigned short f2bf(float f) {
    union { float f; unsigned int i; } u; u.f = f;
    unsigned int r = u.i + 0x7fff + ((u.i >> 16) & 1);   // RNE (finite data only)
    return (unsigned short)(r >> 16);
}

// ---------- kernel 0: W fp32 [K][N] -> bf16 transposed wt [N][K] ----------
__global__ __launch_bounds__(256) void wconv_kernel(
    const float* __restrict__ weight, unsigned short* __restrict__ wt) {
  int id = blockIdx.x * 256 + threadIdx.x;   // 32768 = 256*128
  int col = id & 127;
  int k   = id >> 7;
  wt[(size_t)col * IN_F + k] = f2bf(weight[(size_t)k * OUT_F + col]);
}

// ---------- kernel 1: support = X @ W via MFMA -> int8 two-slab + scale ----
// Slab layout (per 64-B row): byte b holds col (b&3)*16 + (b>>2)  [+64 slabB].
// Each MFMA lane stores its nt=0..3 bytes to slabA, nt=4..7 to slabB,
// both contiguous at byte offset l15*4 — no LDS repack needed.
#define XS 72
#define WSS 72
__global__ __launch_bounds__(256) void gemm_xw_mfma(
    const float* __restrict__ x, const unsigned short* __restrict__ wt,
    unsigned char* __restrict__ slabA /* [N_NODES][64] int8 */,
    unsigned char* __restrict__ slabB /* [N_NODES][64] int8 */,
    float* __restrict__ scales /* [N_NODES] */) {
  __shared__ unsigned short smem[13824];
  unsigned short* Xt = smem;           // [64][XS]
  unsigned short* Wt = smem + 4608;    // [128][WSS]

  const int tid  = threadIdx.x;
  const int w    = tid >> 6;
  const int lane = tid & 63;
  const int l15  = lane & 15;
  const int lhi  = lane >> 4;
  const int row0 = blockIdx.x * 64;

  f32x4 acc[8];
  #pragma unroll
  for (int nt = 0; nt < 8; ++nt) acc[nt] = (f32x4){0.f, 0.f, 0.f, 0.f};

  for (int ks = 0; ks < 4; ++ks) {
    {
      int r = tid >> 2;
      int srow = row0 + r; if (srow >= N_NODES) srow = N_NODES - 1;
      const float* xp = x + (size_t)srow * IN_F + ks * 64;
      #pragma unroll
      for (int i = 0; i < 4; ++i) {
        int f4 = (tid & 3) + i * 4;          // 0..15
        float4 v = *(const float4*)(xp + f4 * 4);
        ushort4 h;
        h.x = f2bf(v.x); h.y = f2bf(v.y); h.z = f2bf(v.z); h.w = f2bf(v.w);
        *(ushort4*)(&Xt[r * XS + f4 * 4]) = h;
      }
    }
    {
      int c = tid >> 1;
      const unsigned short* wp = wt + (size_t)c * IN_F + ks * 64;
      #pragma unroll
      for (int i = 0; i < 4; ++i) {
        int c8 = (tid & 1) * 4 + i;          // 0..7, 8 bf16 each
        uint4 v = *(const uint4*)(wp + c8 * 8);
        *(uint4*)(&Wt[c * WSS + c8 * 8]) = v;
      }
    }
    __syncthreads();
    #pragma unroll
    for (int kt = 0; kt < 2; ++kt) {
      bf16x8 a = *(const bf16x8*)(&Xt[(w * 16 + l15) * XS + kt * 32 + lhi * 8]);
      #pragma unroll
      for (int nt = 0; nt < 8; ++nt) {
        bf16x8 b = *(const bf16x8*)(&Wt[(nt * 16 + l15) * WSS + kt * 32 + lhi * 8]);
        acc[nt] = __builtin_amdgcn_mfma_f32_16x16x32_bf16(a, b, acc[nt], 0, 0, 0);
      }
    }
    __syncthreads();
  }

  // ---- epilogue: per-row absmax -> int8 quant -> two-slab permuted store
  float m0 = 0.f, m1 = 0.f, m2 = 0.f, m3 = 0.f;
  #pragma unroll
  for (int nt = 0; nt < 8; ++nt) {
    m0 = fmaxf(m0, fabsf(acc[nt][0]));
    m1 = fmaxf(m1, fabsf(acc[nt][1]));
    m2 = fmaxf(m2, fabsf(acc[nt][2]));
    m3 = fmaxf(m3, fabsf(acc[nt][3]));
  }
  #pragma unroll
  for (int off = 1; off <= 8; off <<= 1) {
    m0 = fmaxf(m0, __shfl_xor(m0, off, 64));
    m1 = fmaxf(m1, __shfl_xor(m1, off, 64));
    m2 = fmaxf(m2, __shfl_xor(m2, off, 64));
    m3 = fmaxf(m3, __shfl_xor(m3, off, 64));
  }
  #pragma unroll
  for (int r = 0; r < 4; ++r) {
    float m = (r == 0) ? m0 : (r == 1) ? m1 : (r == 2) ? m2 : m3;
    float inv = m > 0.f ? 127.0f / m : 0.f;
    unsigned int lo = 0, hi = 0;
    #pragma unroll
    for (int nt = 0; nt < 4; ++nt) {
      int q = (int)rintf(acc[nt][r] * inv);
      lo |= ((unsigned int)(q & 255)) << (8 * nt);
    }
    #pragma unroll
    for (int nt = 4; nt < 8; ++nt) {
      int q = (int)rintf(acc[nt][r] * inv);
      hi |= ((unsigned int)(q & 255)) << (8 * (nt - 4));
    }
    int row = row0 + w * 16 + lhi * 4 + r;
    if (row < N_NODES) {
      *(unsigned int*)(slabA + (size_t)row * 64 + l15 * 4) = lo;
      *(unsigned int*)(slabB + (size_t)row * 64 + l15 * 4) = hi;
    }
  }
  if (l15 < 4) {
    float m = (l15 == 0) ? m0 : (l15 == 1) ? m1 : (l15 == 2) ? m2 : m3;
    int row = row0 + w * 16 + lhi * 4 + l15;
    if (row < N_NODES) scales[row] = m * (1.0f / 127.0f);
  }
}

// ---------- kernel 2: row_ptr via binary search (edge_row is sorted) ----------
__global__ __launch_bounds__(256) void rowptr_kernel(
    const int* __restrict__ edge_row, int* __restrict__ row_ptr) {
  int r = blockIdx.x * 256 + threadIdx.x;
  if (r > N_NODES) return;
  int lo = 0, hi = N_EDGES;
  while (lo < hi) {
    int mid = (lo + hi) >> 1;
    if (edge_row[mid] < r) lo = mid + 1; else hi = mid;
  }
  row_ptr[r] = lo;  // first edge with row >= r
}

// ---------- kernel 3: CSR SpMM over one 64-B slab (launched twice) ----------
// Wave per row; lane = esl(2b) | fg(4b): 16 lanes x 4 B = full 64-B slab row,
// 4 edges per gather instruction, 4 independent gathers (16 edges, 16 lines)
// in flight. Per-phase gather working set = 6.4 MB -> ~60% per-XCD L2 hit.
// Kernel boundary between phases keeps all XCDs on the same slab.
__global__ __launch_bounds__(256) void spmm_phase_kernel(
    const unsigned char* __restrict__ slab,   // [N_NODES][64] permuted int8
    const float* __restrict__ scales,         // [N_NODES]
    const int* __restrict__ row_ptr,
    const int* __restrict__ edge_col,
    const float* __restrict__ edge_val,
    const float* __restrict__ bias,
    float* __restrict__ out, int coff /* 0 or 64 */) {
  int row = (blockIdx.x * 256 + threadIdx.x) >> 6;   // wave-uniform
  row = __builtin_amdgcn_readfirstlane(row);
  if (row >= N_NODES) return;
  const int lane = threadIdx.x & 63;
  const int esl  = lane >> 4;        // edge slot 0..3
  const int fg   = lane & 15;        // byte group: bytes fg*4..fg*4+3

  // this lane's 4 output columns: col_j = coff + j*16 + fg
  const float b0 = bias[coff + fg],      b1 = bias[coff + 16 + fg];
  const float b2 = bias[coff + 32 + fg], b3 = bias[coff + 48 + fg];

  int e = row_ptr[row];
  int t = row_ptr[row + 1];
  float a0 = 0.f, a1 = 0.f, a2 = 0.f, a3 = 0.f;

  while (e < t) {
    const int tm1 = t - 1;
#define EDGE_LD(g) \
    int   ei##g = e + esl + 4 * g; \
    int   j##g  = ei##g < t ? ei##g : tm1; \
    int   c##g  = edge_col[j##g]; \
    float v##g  = ei##g < t ? edge_val[j##g] : 0.f;
    EDGE_LD(0) EDGE_LD(1) EDGE_LD(2) EDGE_LD(3)
#undef EDGE_LD
    float sc0 = scales[c0], sc1 = scales[c1];
    float sc2 = scales[c2], sc3 = scales[c3];
#define GATH(g) \
    unsigned int s##g = *(const unsigned int*)(slab + (size_t)c##g * 64 + fg * 4);
    GATH(0) GATH(1) GATH(2) GATH(3)
#undef GATH
#define ACC(g) { \
    float wv = v##g * sc##g; int s = (int)s##g; \
    a0 += wv * (float)((s << 24) >> 24); \
    a1 += wv * (float)((s << 16) >> 24); \
    a2 += wv * (float)((s <<  8) >> 24); \
    a3 += wv * (float)( s        >> 24); }
    ACC(0) ACC(1) ACC(2) ACC(3)
#undef ACC
    e += 16;
  }

  // reduce across the 4 edge slots (lane bits 4..5)
  a0 += __shfl_xor(a0, 16, 64); a0 += __shfl_xor(a0, 32, 64);
  a1 += __shfl_xor(a1, 16, 64); a1 += __shfl_xor(a1, 32, 64);
  a2 += __shfl_xor(a2, 16, 64); a2 += __shfl_xor(a2, 32, 64);
  a3 += __shfl_xor(a3, 16, 64); a3 += __shfl_xor(a3, 32, 64);

  if (lane < 16) {
    float* op = out + (size_t)row * OUT_F + coff + fg;
    op[0]  = a0 + b0;
    op[16] = a1 + b1;
    op[32] = a2 + b2;
    op[48] = a3 + b3;
  }
}

// ---------- launch ----------
extern "C" void kernel_launch(void* const* d_in, const int* in_sizes, int n_in,
                              void* d_out, int out_size, void* d_ws, size_t ws_size,
                              hipStream_t stream) {
  const float* x        = (const float*)d_in[0];
  const int*   edge_row = (const int*)  d_in[1];
  const int*   edge_col = (const int*)  d_in[2];
  const float* edge_val = (const float*)d_in[3];
  const float* weight   = (const float*)d_in[4];
  const float* bias     = (const float*)d_in[5];
  float* out = (float*)d_out;

  unsigned char* ws = (unsigned char*)d_ws;
  size_t slab_bytes = (size_t)N_NODES * 64;                      // 6.4 MB each
  unsigned char* slabA = ws;
  unsigned char* slabB = ws + ((slab_bytes + 255) & ~(size_t)255);
  size_t rp_off = 2 * ((slab_bytes + 255) & ~(size_t)255);
  int* row_ptr = (int*)(ws + rp_off);
  size_t wt_off = (rp_off + (size_t)(N_NODES + 1) * 4 + 255) & ~(size_t)255;
  unsigned short* wt = (unsigned short*)(ws + wt_off);
  size_t sc_off = (wt_off + (size_t)IN_F * OUT_F * 2 + 255) & ~(size_t)255;
  float* scales = (float*)(ws + sc_off);

  hipLaunchKernelGGL(rowptr_kernel, dim3((N_NODES + 1 + 255) / 256), dim3(256), 0, stream,
                     edge_row, row_ptr);
  hipLaunchKernelGGL(wconv_kernel, dim3(128), dim3(256), 0, stream,
                     weight, wt);
  hipLaunchKernelGGL(gemm_xw_mfma, dim3((N_NODES + 63) / 64), dim3(256), 0, stream,
                     x, wt, slabA, slabB, scales);
  hipLaunchKernelGGL(spmm_phase_kernel, dim3(N_NODES / 4), dim3(256), 0, stream,
                     slabA, scales, row_ptr, edge_col, edge_val, bias, out, 0);
  hipLaunchKernelGGL(spmm_phase_kernel, dim3(N_NODES / 4), dim3(256), 0, stream,
                     slabB, scales, row_ptr, edge_col, edge_val, bias, out, 64);
}

// Round 11
// 87.611 us; speedup vs baseline: 1.2611x; 1.2611x over previous
//
#include <hip/hip_runtime.h>
#include <hip/hip_bf16.h>

#define N_NODES 100000
#define N_EDGES 1600000
#define IN_F 256
#define OUT_F 128

typedef __attribute__((ext_vector_type(8))) __bf16 bf16x8;
typedef __attribute__((ext_vector_type(4))) float f32x4;

__device__ __forceinline__ unsigned short f2bf(float f) {
    union { float f; unsigned int i; } u; u.f = f;
    unsigned int r = u.i + 0x7fff + ((u.i >> 16) & 1);   // RNE (finite data only)
    return (unsigned short)(r >> 16);
}

// ---------- kernel 0: W fp32 [K][N] -> bf16 transposed wt [N][K] ----------
__global__ __launch_bounds__(256) void wconv_kernel(
    const float* __restrict__ weight, unsigned short* __restrict__ wt) {
  int id = blockIdx.x * 256 + threadIdx.x;   // 32768 = 256*128
  int col = id & 127;
  int k   = id >> 7;
  wt[(size_t)col * IN_F + k] = f2bf(weight[(size_t)k * OUT_F + col]);
}

// ---------- kernel 1: support = X @ W via MFMA -> int8 + per-row scale ----
// int8 row layout is PERMUTED: byte b of a row holds col (b&7)*16 + (b>>3),
// so each MFMA lane (holding cols nt*16+l15, nt=0..7) stores its 8 bytes
// contiguously at byte offset l15*8. spmm un-permutes on output.
#define XS 72
#define WSS 72
__global__ __launch_bounds__(256) void gemm_xw_mfma(
    const float* __restrict__ x, const unsigned short* __restrict__ wt,
    unsigned char* __restrict__ support_q /* [N_NODES][128] int8 */,
    float* __restrict__ scales /* [N_NODES] */) {
  __shared__ unsigned short smem[13824];
  unsigned short* Xt = smem;           // [64][XS]
  unsigned short* Wt = smem + 4608;    // [128][WSS]

  const int tid  = threadIdx.x;
  const int w    = tid >> 6;
  const int lane = tid & 63;
  const int l15  = lane & 15;
  const int lhi  = lane >> 4;
  const int row0 = blockIdx.x * 64;

  f32x4 acc[8];
  #pragma unroll
  for (int nt = 0; nt < 8; ++nt) acc[nt] = (f32x4){0.f, 0.f, 0.f, 0.f};

  for (int ks = 0; ks < 4; ++ks) {
    {
      int r = tid >> 2;
      int srow = row0 + r; if (srow >= N_NODES) srow = N_NODES - 1;
      const float* xp = x + (size_t)srow * IN_F + ks * 64;
      #pragma unroll
      for (int i = 0; i < 4; ++i) {
        int f4 = (tid & 3) + i * 4;          // 0..15
        float4 v = *(const float4*)(xp + f4 * 4);
        ushort4 h;
        h.x = f2bf(v.x); h.y = f2bf(v.y); h.z = f2bf(v.z); h.w = f2bf(v.w);
        *(ushort4*)(&Xt[r * XS + f4 * 4]) = h;
      }
    }
    {
      int c = tid >> 1;
      const unsigned short* wp = wt + (size_t)c * IN_F + ks * 64;
      #pragma unroll
      for (int i = 0; i < 4; ++i) {
        int c8 = (tid & 1) * 4 + i;          // 0..7, 8 bf16 each
        uint4 v = *(const uint4*)(wp + c8 * 8);
        *(uint4*)(&Wt[c * WSS + c8 * 8]) = v;
      }
    }
    __syncthreads();
    #pragma unroll
    for (int kt = 0; kt < 2; ++kt) {
      bf16x8 a = *(const bf16x8*)(&Xt[(w * 16 + l15) * XS + kt * 32 + lhi * 8]);
      #pragma unroll
      for (int nt = 0; nt < 8; ++nt) {
        bf16x8 b = *(const bf16x8*)(&Wt[(nt * 16 + l15) * WSS + kt * 32 + lhi * 8]);
        acc[nt] = __builtin_amdgcn_mfma_f32_16x16x32_bf16(a, b, acc[nt], 0, 0, 0);
      }
    }
    __syncthreads();
  }

  // ---- epilogue: per-row absmax -> int8 quant -> permuted-contiguous store
  float m0 = 0.f, m1 = 0.f, m2 = 0.f, m3 = 0.f;
  #pragma unroll
  for (int nt = 0; nt < 8; ++nt) {
    m0 = fmaxf(m0, fabsf(acc[nt][0]));
    m1 = fmaxf(m1, fabsf(acc[nt][1]));
    m2 = fmaxf(m2, fabsf(acc[nt][2]));
    m3 = fmaxf(m3, fabsf(acc[nt][3]));
  }
  #pragma unroll
  for (int off = 1; off <= 8; off <<= 1) {
    m0 = fmaxf(m0, __shfl_xor(m0, off, 64));
    m1 = fmaxf(m1, __shfl_xor(m1, off, 64));
    m2 = fmaxf(m2, __shfl_xor(m2, off, 64));
    m3 = fmaxf(m3, __shfl_xor(m3, off, 64));
  }
  #pragma unroll
  for (int r = 0; r < 4; ++r) {
    float m = (r == 0) ? m0 : (r == 1) ? m1 : (r == 2) ? m2 : m3;
    float inv = m > 0.f ? 127.0f / m : 0.f;
    unsigned int lo = 0, hi = 0;
    #pragma unroll
    for (int nt = 0; nt < 4; ++nt) {
      int q = (int)rintf(acc[nt][r] * inv);
      lo |= ((unsigned int)(q & 255)) << (8 * nt);
    }
    #pragma unroll
    for (int nt = 4; nt < 8; ++nt) {
      int q = (int)rintf(acc[nt][r] * inv);
      hi |= ((unsigned int)(q & 255)) << (8 * (nt - 4));
    }
    int row = row0 + w * 16 + lhi * 4 + r;
    if (row < N_NODES) {
      uint2 p; p.x = lo; p.y = hi;
      *(uint2*)(support_q + (size_t)row * 128 + l15 * 8) = p;
    }
  }
  if (l15 < 4) {
    float m = (l15 == 0) ? m0 : (l15 == 1) ? m1 : (l15 == 2) ? m2 : m3;
    int row = row0 + w * 16 + lhi * 4 + l15;
    if (row < N_NODES) scales[row] = m * (1.0f / 127.0f);
  }
}

// ---------- kernel 2: row_ptr via binary search (edge_row is sorted) ----------
__global__ __launch_bounds__(256) void rowptr_kernel(
    const int* __restrict__ edge_row, int* __restrict__ row_ptr) {
  int r = blockIdx.x * 256 + threadIdx.x;
  if (r > N_NODES) return;
  int lo = 0, hi = N_EDGES;
  while (lo < hi) {
    int mid = (lo + hi) >> 1;
    if (edge_row[mid] < r) lo = mid + 1; else hi = mid;
  }
  row_ptr[r] = lo;  // first edge with row >= r
}

// ---------- kernel 3: CSR SpMM on int8 support ----------
// wave per row; lane = eslot(1b) | fg(5b): 2 edges per gather, 32 lanes x 4 B
// = 128 B (full row) per edge. 8 independent gathers (16 edges) in flight.
// Dequant: w = val * scale[col]; 4x (sext-bfe, cvt, fma).
__global__ __launch_bounds__(256) void spmm_kernel(
    const unsigned char* __restrict__ support_q,  // [N_NODES][128] permuted int8
    const float* __restrict__ scales,             // [N_NODES]
    const int* __restrict__ row_ptr,
    const int* __restrict__ edge_col,
    const float* __restrict__ edge_val,
    const float* __restrict__ bias,
    float* __restrict__ out) {
  int row = (blockIdx.x * 256 + threadIdx.x) >> 6;   // wave-uniform
  row = __builtin_amdgcn_readfirstlane(row);
  if (row >= N_NODES) return;
  const int lane = threadIdx.x & 63;
  const int esl  = lane >> 5;        // edge slot 0..1
  const int fg   = lane & 31;        // feature group: bytes 4fg..4fg+3

  // un-permuted output columns for this lane's 4 bytes
  const int cbase = (fg & 1) * 64 + (fg >> 1);
  const int c0o = cbase, c1o = cbase + 16, c2o = cbase + 32, c3o = cbase + 48;
  const float b0 = bias[c0o], b1 = bias[c1o], b2 = bias[c2o], b3 = bias[c3o];

  int e   = row_ptr[row];
  int end = row_ptr[row + 1];
  float a0 = 0.f, a1 = 0.f, a2 = 0.f, a3 = 0.f;

  while (e < end) {
    const int tm1 = end - 1;
#define EDGE_LD(g) \
    int   ei##g = e + 2 * g + esl; \
    int   j##g  = ei##g < end ? ei##g : tm1; \
    int   c##g  = edge_col[j##g]; \
    float v##g  = ei##g < end ? edge_val[j##g] : 0.f;
    EDGE_LD(0) EDGE_LD(1) EDGE_LD(2) EDGE_LD(3)
    EDGE_LD(4) EDGE_LD(5) EDGE_LD(6) EDGE_LD(7)
#undef EDGE_LD
#define GATH(g) \
    unsigned int s##g = *(const unsigned int*)(support_q + (size_t)c##g * 128 + fg * 4); \
    float sc##g = scales[c##g];
    GATH(0) GATH(1) GATH(2) GATH(3)
    GATH(4) GATH(5) GATH(6) GATH(7)
#undef GATH
#define ACCUM(g) { \
    float wv = v##g * sc##g; \
    a0 += wv * (float)(((int)(s##g << 24)) >> 24); \
    a1 += wv * (float)(((int)(s##g << 16)) >> 24); \
    a2 += wv * (float)(((int)(s##g <<  8)) >> 24); \
    a3 += wv * (float)(((int)s##g) >> 24); }
    ACCUM(0) ACCUM(1) ACCUM(2) ACCUM(3)
    ACCUM(4) ACCUM(5) ACCUM(6) ACCUM(7)
#undef ACCUM
    e += 16;
  }

  // combine the two edge-slot halves
  a0 += __shfl_xor(a0, 32, 64);
  a1 += __shfl_xor(a1, 32, 64);
  a2 += __shfl_xor(a2, 32, 64);
  a3 += __shfl_xor(a3, 32, 64);

  if (lane < 32) {
    float* op = out + (size_t)row * OUT_F;
    op[c0o] = a0 + b0;
    op[c1o] = a1 + b1;
    op[c2o] = a2 + b2;
    op[c3o] = a3 + b3;
  }
}

// ---------- launch ----------
extern "C" void kernel_launch(void* const* d_in, const int* in_sizes, int n_in,
                              void* d_out, int out_size, void* d_ws, size_t ws_size,
                              hipStream_t stream) {
  const float* x        = (const float*)d_in[0];
  const int*   edge_row = (const int*)  d_in[1];
  const int*   edge_col = (const int*)  d_in[2];
  const float* edge_val = (const float*)d_in[3];
  const float* weight   = (const float*)d_in[4];
  const float* bias     = (const float*)d_in[5];
  float* out = (float*)d_out;

  unsigned char* ws = (unsigned char*)d_ws;
  size_t sq_bytes = (size_t)N_NODES * 128;                       // 12.8 MB int8
  unsigned char* support_q = ws;
  size_t rp_off = (sq_bytes + 255) & ~(size_t)255;
  int* row_ptr = (int*)(ws + rp_off);
  size_t wt_off = (rp_off + (size_t)(N_NODES + 1) * 4 + 255) & ~(size_t)255;
  unsigned short* wt = (unsigned short*)(ws + wt_off);
  size_t sc_off = (wt_off + (size_t)IN_F * OUT_F * 2 + 255) & ~(size_t)255;
  float* scales = (float*)(ws + sc_off);

  hipLaunchKernelGGL(rowptr_kernel, dim3((N_NODES + 1 + 255) / 256), dim3(256), 0, stream,
                     edge_row, row_ptr);
  hipLaunchKernelGGL(wconv_kernel, dim3(128), dim3(256), 0, stream,
                     weight, wt);
  hipLaunchKernelGGL(gemm_xw_mfma, dim3((N_NODES + 63) / 64), dim3(256), 0, stream,
                     x, wt, support_q, scales);
  hipLaunchKernelGGL(spmm_kernel, dim3(N_NODES / 4), dim3(256), 0, stream,
                     support_q, scales, row_ptr, edge_col, edge_val, bias, out);
}